// Round 11
// baseline (362.762 us; speedup 1.0000x reference)
//
#include <hip/hip_runtime.h>
#include <math.h>

#define TMAX 16384
#define MDIM 16
#define CLEN 16      // steps per chunk
#define WUP  8       // warmup steps (R9/R10 proved 16 exact; 8 predicted err << bf16 ULP)
#define CHKB 512     // blocks; each runs chunks 2b, 2b+1
#define NS   (CLEN + WUP - 1)     // 23 steps per chunk
#define NROWS (2 * CLEN + WUP)    // 40 P rows per block, row(k) = 32b - WUP + k
#define HROWS 20                  // em phase half size

typedef unsigned int  uint;
typedef unsigned short ushort;
typedef __attribute__((ext_vector_type(8))) short short8;
typedef __attribute__((ext_vector_type(4))) short short4v;
typedef __attribute__((ext_vector_type(4))) float floatx4;
typedef __attribute__((ext_vector_type(2))) uint uintx2;

// ---- DPP-based full-wave (64-lane) max ----
template<int CTRL>
__device__ __forceinline__ float fmax_dpp(float v) {
    int o = __builtin_amdgcn_update_dpp(__float_as_int(v), __float_as_int(v),
                                        CTRL, 0xf, 0xf, false);
    return fmaxf(v, __int_as_float(o));
}
__device__ __forceinline__ float waveMax64(float v) {
    v = fmax_dpp<0x111>(v);
    v = fmax_dpp<0x112>(v);
    v = fmax_dpp<0x114>(v);
    v = fmax_dpp<0x118>(v);
    v = fmax_dpp<0x142>(v);
    v = fmax_dpp<0x143>(v);
    return __int_as_float(__builtin_amdgcn_readlane(__float_as_int(v), 63));
}
__device__ __forceinline__ float waveSumF(float v) {
    #pragma unroll
    for (int o = 32; o > 0; o >>= 1) v += __shfl_xor(v, o, 64);
    return v;
}
__device__ __forceinline__ double waveSumD(double v) {
    #pragma unroll
    for (int o = 32; o > 0; o >>= 1) v += __shfl_xor(v, o, 64);
    return v;
}

// bf16 helpers (RNE emulation — bit-exact, harness-proven)
__device__ __forceinline__ short f2bfs(float f) {
    uint u = __float_as_uint(f);
    return (short)((u + 0x7FFFu + ((u >> 16) & 1u)) >> 16);
}
__device__ __forceinline__ uint pkbf(float a, float b) {
    uint ua = __float_as_uint(a), ub = __float_as_uint(b);
    ua = (ua + 0x7FFFu + ((ua >> 16) & 1u)) >> 16;
    ub = (ub + 0x7FFFu + ((ub >> 16) & 1u)) & 0xFFFF0000u;
    return ua | ub;
}
__device__ __forceinline__ short4v pk4(float a, float b, float c, float d) {
    short4v r;
    r[0] = f2bfs(a); r[1] = f2bfs(b); r[2] = f2bfs(c); r[3] = f2bfs(d);
    return r;
}
__device__ __forceinline__ float bfl(uint u) { return __uint_as_float(u << 16); }
__device__ __forceinline__ float bfh(uint u) { return __uint_as_float(u & 0xFFFF0000u); }

// K=16 bf16 MFMA
#if __has_builtin(__builtin_amdgcn_mfma_f32_16x16x16bf16_1k)
#define MFMA16(a, b, c) __builtin_amdgcn_mfma_f32_16x16x16bf16_1k(a, b, c, 0, 0, 0)
#else
__device__ __forceinline__ floatx4 mfma16_asm(short4v a, short4v b, floatx4 c) {
    asm volatile("v_mfma_f32_16x16x16_bf16 %0, %1, %2, %0\n\t"
                 "s_nop 7\n\ts_nop 7"
                 : "+v"(c) : "v"(a), "v"(b));
    return c;
}
#define MFMA16(a, b, c) mfma16_asm(a, b, c)
#endif
#define MFMA32(a, b, c) __builtin_amdgcn_mfma_f32_16x16x32_bf16(a, b, c, 0, 0, 0)

// ---- FUSED kernel: em+P in registers, then the R10-verified 2-chunk loop.
// R10 post-mortem: P-buffer roundtrip (64MB write @2.1TB/s with 2.125x
// amplification + 68MB read) was ~half the total. Fusion keeps P in Pr[40]
// registers (emP's slot map already made producer thread == consumer thread).
// em phase: 40 rows in 2 halves of 20 (R7-proven structure), row-max Dem via
// block reduce — Dem is bitwise identical across blocks sharing a row (same
// inputs, same FMA order) so per-block owner accounting (rows [32b,32b+32),
// k=WUP..39) is exact. fhmm loop: R10 SSTEP with Pr[s+KOFFA]/Pr[s+16] replacing
// global prefetch; FULLY UNROLLED so all register indices are compile-time
// (rule #20); KOFFA=8 variant for b=0 (exact pi init at row 0).
__global__ __launch_bounds__(512, 4)
void fhmm_fused_kernel(const int* __restrict__ x,
                       const float* __restrict__ lam1,
                       const float* __restrict__ lam2,
                       const float* __restrict__ lam3,
                       const float* __restrict__ logA1,
                       const float* __restrict__ logA2,
                       const float* __restrict__ logA3,
                       const float* __restrict__ logpi1,
                       const float* __restrict__ logpi2,
                       const float* __restrict__ logpi3,
                       float* __restrict__ out)
{
    __shared__ __align__(16) short c1bA[2 * 2048];   // chunk A parity double buffer
    __shared__ __align__(16) short c1bB[2 * 2048];   // chunk B parity double buffer
    __shared__ float wmAA[8], wmAB[8];               // odd steps write, even read
    __shared__ float sred[8];
    __shared__ float wmx[HROWS][8];
    __shared__ float DemS[NROWS];
    __shared__ float lgtbl[32];
    __shared__ __align__(16) float xfs[NROWS * MDIM];   // 640 floats
    __shared__ float lgred;

    const int tid  = threadIdx.x;
    const int lane = tid & 63;
    const int wv   = tid >> 6;
    const int q    = lane >> 4;
    const int ml   = lane & 15;
    const int d2   = 2 * wv + (ml >> 3);
    const int d3   = ml & 7;

    const int b     = blockIdx.x;
    const int rbase = 32 * b - WUP;      // row(k) = rbase + k

    if (tid < 32) lgtbl[tid] = lgammaf((float)tid + 1.0f);
    if (tid == 0) lgred = 0.f;

    // x -> float LDS for 40 rows (clamp negative rows for b=0; k<WUP unused there)
    {
        int g0 = rbase + (tid >> 4);
        if (g0 < 0) g0 = 0;
        xfs[tid] = (float)x[g0 * MDIM + (tid & 15)];
        if (tid < NROWS * MDIM - 512) {
            int i = tid + 512;                 // i>=512 -> row>=32 -> always >=0
            xfs[i] = (float)x[(rbase + (i >> 4)) * MDIM + (i & 15)];
        }
    }

    // per-thread log-lambda table for its 4 states (same mapping as consumption)
    float llc[4][16], ls[4];
    #pragma unroll
    for (int j = 0; j < 4; ++j) {
        const int d1 = 4 * q + j;
        float sum = 0.f;
        #pragma unroll
        for (int m = 0; m < 16; ++m) {
            float la = lam1[d1 * 16 + m] + lam2[d2 * 16 + m] + lam3[d3 * 16 + m];
            sum += la;
            llc[j][m] = __logf(la);
        }
        ls[j] = sum;
    }
    __syncthreads();   // xfs + lgtbl + lgred ready

    // lgamma over OWNER rows [32b, 32b+32): one int per thread
    {
        int xv = x[32 * b * MDIM + tid];
        double lg = (double)lgtbl[xv & 31];
        lg = waveSumD(lg);
        if (lane == 0) atomicAdd(&lgred, (float)lg);
    }

    // ---- em phase: Pr[40] in registers, 2 halves of 20 rows (R7 structure) ----
    uintx2 Pr[NROWS];
    float em[HROWS][4];
    #pragma unroll
    for (int h = 0; h < 2; ++h) {
        #pragma unroll
        for (int r = 0; r < HROWS; ++r) {
            const int k = HROWS * h + r;
            float xr[16];
            *(float4*)&xr[0]  = *(const float4*)&xfs[k * 16 + 0];
            *(float4*)&xr[4]  = *(const float4*)&xfs[k * 16 + 4];
            *(float4*)&xr[8]  = *(const float4*)&xfs[k * 16 + 8];
            *(float4*)&xr[12] = *(const float4*)&xfs[k * 16 + 12];
            float vm = -3.4e38f;
            #pragma unroll
            for (int j = 0; j < 4; ++j) {
                float d = 0.f;
                #pragma unroll
                for (int m = 0; m < 16; ++m) d = fmaf(xr[m], llc[j][m], d);
                em[r][j] = d - ls[j];
                vm = fmaxf(vm, em[r][j]);
            }
            vm = waveMax64(vm);
            if (lane == 0) wmx[r][wv] = vm;
        }
        __syncthreads();
        if (tid < HROWS) {
            float m = wmx[tid][0];
            #pragma unroll
            for (int i = 1; i < 8; ++i) m = fmaxf(m, wmx[tid][i]);
            DemS[HROWS * h + tid] = m;
        }
        __syncthreads();
        #pragma unroll
        for (int r = 0; r < HROWS; ++r) {
            const int k = HROWS * h + r;
            const float Dem = DemS[k];
            uintx2 w;
            w.x = pkbf(__expf(em[r][0] - Dem), __expf(em[r][1] - Dem));
            w.y = pkbf(__expf(em[r][2] - Dem), __expf(em[r][3] - Dem));
            Pr[k] = w;
        }
    }

    // ---- fhmm constants (R9/R10-verified) ----
    short4v bA1k;
    #pragma unroll
    for (int j = 0; j < 4; ++j)
        bA1k[j] = f2bfs(__expf(logA1[ml * 16 + 4 * q + j]));
    short8 bK[4];
    #pragma unroll
    for (int jc = 0; jc < 4; ++jc)
        #pragma unroll
        for (int i = 0; i < 8; ++i)
            bK[jc][i] = f2bfs(__expf(logA2[d2 * 16 + 4 * jc + q] + logA3[d3 * 8 + i]));
    const int oS1w = ml * 128 + ((((2 * wv + (q >> 1)) ^ ml) & 15) << 3) + 4 * (q & 1);
    int o23[4];
    #pragma unroll
    for (int jc = 0; jc < 4; ++jc)
        o23[jc] = ml * 128 + ((((4 * jc + q) ^ ml) & 15) << 3);

    // ---- init chunks: A at k=0 (b>0) / k=WUP with pi (b=0); B at k=CLEN ----
    double OFF = 0.0;
    float nuA0, nuA1, nuA2, nuA3, nuB0, nuB1, nuB2, nuB3;
    if (b == 0) {
        uintx2 p0 = Pr[WUP];     // row 0, exact: beta_0 = P_0 * pi
        float lp23 = logpi2[d2] + logpi3[d3];
        nuA0 = bfl(p0.x) * __expf(logpi1[4 * q + 0] + lp23);
        nuA1 = bfh(p0.x) * __expf(logpi1[4 * q + 1] + lp23);
        nuA2 = bfl(p0.y) * __expf(logpi1[4 * q + 2] + lp23);
        nuA3 = bfh(p0.y) * __expf(logpi1[4 * q + 3] + lp23);
    } else {
        uintx2 p0 = Pr[0];       // warm-start
        nuA0 = bfl(p0.x); nuA1 = bfh(p0.x);
        nuA2 = bfl(p0.y); nuA3 = bfh(p0.y);
    }
    {
        uintx2 p0 = Pr[CLEN];    // chunk B warm-start, row 32b+WUP? no: row rbase+16 = 32b+8
        nuB0 = bfl(p0.x); nuB1 = bfh(p0.x);
        nuB2 = bfl(p0.y); nuB3 = bfh(p0.y);
    }

// One SUPER-step (R10 body, P from registers). S, RESC, KOFFA all compile-time.
#define SSTEP(S, RESC, KOFFA)                                                   \
{                                                                               \
    const int par = (S) & 1;                                                    \
    short* cAq = c1bA + (par << 11);                                            \
    short* cBq = c1bB + (par << 11);                                            \
    {   /* Stage 1, both chunks */                                              \
        short4v afA = pk4(nuA0, nuA1, nuA2, nuA3);                              \
        short4v afB = pk4(nuB0, nuB1, nuB2, nuB3);                              \
        floatx4 sA = {0.f, 0.f, 0.f, 0.f};                                      \
        floatx4 sB = {0.f, 0.f, 0.f, 0.f};                                      \
        sA = MFMA16(afA, bA1k, sA);                                             \
        sB = MFMA16(afB, bA1k, sB);                                             \
        ((uintx2*)(cAq + oS1w))[0] = (uintx2){pkbf(sA[0], sA[1]), pkbf(sA[2], sA[3])}; \
        ((uintx2*)(cBq + oS1w))[0] = (uintx2){pkbf(sB[0], sB[1]), pkbf(sB[2], sB[3])}; \
    }                                                                           \
    __syncthreads();                                                            \
    float invA = 1.f, invB = 1.f;                                               \
    if (RESC) {                                                                 \
        float mpA = waveMax64(wmAA[lane & 7]);                                  \
        float mpB = waveMax64(wmAB[lane & 7]);                                  \
        float mgA = fmaxf(mpA, 1e-30f);                                         \
        float mgB = fmaxf(mpB, 1e-30f);                                         \
        invA = __builtin_amdgcn_rcpf(mgA);                                      \
        invB = __builtin_amdgcn_rcpf(mgB);                                      \
        if (tid == 0) {                                                         \
            if ((KOFFA) == WUP || (S) > WUP) OFF += (double)__logf(mgA);        \
            if ((S) > WUP)                   OFF += (double)__logf(mgB);        \
        }                                                                       \
    }                                                                           \
    {   /* Stage 2+3, both chunks */                                            \
        short8 fA0 = *(const short8*)(cAq + o23[0]);                            \
        short8 fA1 = *(const short8*)(cAq + o23[1]);                            \
        short8 fA2 = *(const short8*)(cAq + o23[2]);                            \
        short8 fA3 = *(const short8*)(cAq + o23[3]);                            \
        short8 fB0 = *(const short8*)(cBq + o23[0]);                            \
        short8 fB1 = *(const short8*)(cBq + o23[1]);                            \
        short8 fB2 = *(const short8*)(cBq + o23[2]);                            \
        short8 fB3 = *(const short8*)(cBq + o23[3]);                            \
        floatx4 aA0 = {0.f, 0.f, 0.f, 0.f};                                     \
        floatx4 aA1 = {0.f, 0.f, 0.f, 0.f};                                     \
        floatx4 aB0 = {0.f, 0.f, 0.f, 0.f};                                     \
        floatx4 aB1 = {0.f, 0.f, 0.f, 0.f};                                     \
        aA0 = MFMA32(fA0, bK[0], aA0);  aB0 = MFMA32(fB0, bK[0], aB0);          \
        aA1 = MFMA32(fA1, bK[1], aA1);  aB1 = MFMA32(fB1, bK[1], aB1);          \
        aA0 = MFMA32(fA2, bK[2], aA0);  aB0 = MFMA32(fB2, bK[2], aB0);          \
        aA1 = MFMA32(fA3, bK[3], aA1);  aB1 = MFMA32(fB3, bK[3], aB1);          \
        floatx4 accA = aA0 + aA1;                                               \
        floatx4 accB = aB0 + aB1;                                               \
        uintx2 PA = Pr[(S) + (KOFFA)];                                          \
        uintx2 PB = Pr[(S) + CLEN];                                             \
        if (RESC) {                                                             \
            nuA0 = bfl(PA.x) * accA[0] * invA;                                  \
            nuA1 = bfh(PA.x) * accA[1] * invA;                                  \
            nuA2 = bfl(PA.y) * accA[2] * invA;                                  \
            nuA3 = bfh(PA.y) * accA[3] * invA;                                  \
            nuB0 = bfl(PB.x) * accB[0] * invB;                                  \
            nuB1 = bfh(PB.x) * accB[1] * invB;                                  \
            nuB2 = bfl(PB.y) * accB[2] * invB;                                  \
            nuB3 = bfh(PB.y) * accB[3] * invB;                                  \
        } else {                                                                \
            nuA0 = bfl(PA.x) * accA[0];                                         \
            nuA1 = bfh(PA.x) * accA[1];                                         \
            nuA2 = bfl(PA.y) * accA[2];                                         \
            nuA3 = bfh(PA.y) * accA[3];                                         \
            nuB0 = bfl(PB.x) * accB[0];                                         \
            nuB1 = bfh(PB.x) * accB[1];                                         \
            nuB2 = bfl(PB.y) * accB[2];                                         \
            nuB3 = bfh(PB.y) * accB[3];                                         \
            float waA = waveMax64(fmaxf(fmaxf(nuA0, nuA1), fmaxf(nuA2, nuA3))); \
            float waB = waveMax64(fmaxf(fmaxf(nuB0, nuB1), fmaxf(nuB2, nuB3))); \
            if (lane == 0) { wmAA[wv] = waA; wmAB[wv] = waB; }                  \
        }                                                                       \
    }                                                                           \
}

    // s = 1..NS(=23); odd prologue, RESC on evens; FULLY UNROLLED (register
    // indices must be compile-time). KOFFA=WUP variant only for b=0.
    if (b == 0) {
        SSTEP(1, false, WUP);
        #pragma unroll
        for (int s2 = 2; s2 < NS; s2 += 2) {
            SSTEP(s2, true, WUP);
            SSTEP(s2 + 1, false, WUP);
        }
    } else {
        SSTEP(1, false, 0);
        #pragma unroll
        for (int s2 = 2; s2 < NS; s2 += 2) {
            SSTEP(s2, true, 0);
            SSTEP(s2 + 1, false, 0);
        }
    }
#undef SSTEP

    __syncthreads();

    // ---- tail: chunk logs + this block's Dem/lgamma partial (owner k=WUP..39)
    if (b == CHKB - 1) {          // chunk B is the global last chunk: sum path
        float su = waveSumF(nuB0 + nuB1 + nuB2 + nuB3);
        if (lane == 0) sred[wv] = su;
        __syncthreads();
        if (tid == 0) {
            float mpA = wmAA[0];
            #pragma unroll
            for (int i = 1; i < 8; ++i) mpA = fmaxf(mpA, wmAA[i]);
            OFF += (double)__logf(fmaxf(mpA, 1e-30f));
            float tot = 0.f;
            #pragma unroll
            for (int i = 0; i < 8; ++i) tot += sred[i];
            OFF += (double)__logf(tot);
            double sumD = 0.0;
            #pragma unroll
            for (int k = WUP; k < NROWS; ++k) sumD += (double)DemS[k];
            OFF += sumD - (double)lgred;
            atomicAdd(out, (float)OFF);
        }
    } else {
        if (tid == 0) {
            float mpA = wmAA[0], mpB = wmAB[0];
            #pragma unroll
            for (int i = 1; i < 8; ++i) {
                mpA = fmaxf(mpA, wmAA[i]);
                mpB = fmaxf(mpB, wmAB[i]);
            }
            OFF += (double)__logf(fmaxf(mpA, 1e-30f));
            OFF += (double)__logf(fmaxf(mpB, 1e-30f));
            double sumD = 0.0;
            #pragma unroll
            for (int k = WUP; k < NROWS; ++k) sumD += (double)DemS[k];
            OFF += sumD - (double)lgred;
            atomicAdd(out, (float)OFF);
        }
    }
}

extern "C" void kernel_launch(void* const* d_in, const int* in_sizes, int n_in,
                              void* d_out, int out_size, void* d_ws, size_t ws_size,
                              hipStream_t stream) {
    const int*   x      = (const int*)  d_in[0];
    const float* lam1   = (const float*)d_in[1];
    const float* lam2   = (const float*)d_in[2];
    const float* lam3   = (const float*)d_in[3];
    const float* logA1  = (const float*)d_in[4];
    const float* logA2  = (const float*)d_in[5];
    const float* logA3  = (const float*)d_in[6];
    const float* logpi1 = (const float*)d_in[7];
    const float* logpi2 = (const float*)d_in[8];
    const float* logpi3 = (const float*)d_in[9];
    float* out = (float*)d_out;

    // workspace unused: P lives in registers now.
    hipMemsetAsync(out, 0, sizeof(float), stream);
    fhmm_fused_kernel<<<dim3(CHKB), dim3(512), 0, stream>>>(
        x, lam1, lam2, lam3, logA1, logA2, logA3, logpi1, logpi2, logpi3, out);
}

// Round 13
// 145.474 us; speedup vs baseline: 2.4937x; 2.4937x over previous
//
#include <hip/hip_runtime.h>
#include <math.h>

#define TMAX 16384
#define MDIM 16
#define SD   2048
#define CLEN 16      // steps per chunk
#define WUP  8       // warmup steps (R9/R10 proved 16; 8 -> boundary err ~2e-4 rel << bf16 ULP)
#define CHKB 512     // fhmm blocks; each runs TWO chunks (cA=2b, cB=2b+1)
#define NS   (CLEN + WUP - 1)   // 23 steps per chunk (odd; s=1 prologue + 11 pairs)
#define EROWS 32     // t-rows per emP block

typedef unsigned int  uint;
typedef unsigned short ushort;
typedef __attribute__((ext_vector_type(8))) short short8;
typedef __attribute__((ext_vector_type(4))) short short4v;
typedef __attribute__((ext_vector_type(4))) float floatx4;
typedef __attribute__((ext_vector_type(2))) uint uintx2;

// ---- DPP-based full-wave (64-lane) max ----
template<int CTRL>
__device__ __forceinline__ float fmax_dpp(float v) {
    int o = __builtin_amdgcn_update_dpp(__float_as_int(v), __float_as_int(v),
                                        CTRL, 0xf, 0xf, false);
    return fmaxf(v, __int_as_float(o));
}
__device__ __forceinline__ float waveMax64(float v) {
    v = fmax_dpp<0x111>(v);
    v = fmax_dpp<0x112>(v);
    v = fmax_dpp<0x114>(v);
    v = fmax_dpp<0x118>(v);
    v = fmax_dpp<0x142>(v);
    v = fmax_dpp<0x143>(v);
    return __int_as_float(__builtin_amdgcn_readlane(__float_as_int(v), 63));
}
__device__ __forceinline__ float waveSumF(float v) {
    #pragma unroll
    for (int o = 32; o > 0; o >>= 1) v += __shfl_xor(v, o, 64);
    return v;
}
__device__ __forceinline__ double waveSumD(double v) {
    #pragma unroll
    for (int o = 32; o > 0; o >>= 1) v += __shfl_xor(v, o, 64);
    return v;
}

// bf16 helpers (RNE emulation — bit-exact, harness-proven)
__device__ __forceinline__ short f2bfs(float f) {
    uint u = __float_as_uint(f);
    return (short)((u + 0x7FFFu + ((u >> 16) & 1u)) >> 16);
}
__device__ __forceinline__ uint pkbf(float a, float b) {
    uint ua = __float_as_uint(a), ub = __float_as_uint(b);
    ua = (ua + 0x7FFFu + ((ua >> 16) & 1u)) >> 16;
    ub = (ub + 0x7FFFu + ((ub >> 16) & 1u)) & 0xFFFF0000u;
    return ua | ub;
}
__device__ __forceinline__ short4v pk4(float a, float b, float c, float d) {
    short4v r;
    r[0] = f2bfs(a); r[1] = f2bfs(b); r[2] = f2bfs(c); r[3] = f2bfs(d);
    return r;
}
__device__ __forceinline__ float bfl(uint u) { return __uint_as_float(u << 16); }
__device__ __forceinline__ float bfh(uint u) { return __uint_as_float(u & 0xFFFF0000u); }

// K=16 bf16 MFMA
#if __has_builtin(__builtin_amdgcn_mfma_f32_16x16x16bf16_1k)
#define MFMA16(a, b, c) __builtin_amdgcn_mfma_f32_16x16x16bf16_1k(a, b, c, 0, 0, 0)
#else
__device__ __forceinline__ floatx4 mfma16_asm(short4v a, short4v b, floatx4 c) {
    asm volatile("v_mfma_f32_16x16x16_bf16 %0, %1, %2, %0\n\t"
                 "s_nop 7\n\ts_nop 7"
                 : "+v"(c) : "v"(a), "v"(b));
    return c;
}
#define MFMA16(a, b, c) mfma16_asm(a, b, c)
#endif
#define MFMA32(a, b, c) __builtin_amdgcn_mfma_f32_16x16x32_bf16(a, b, c, 0, 0, 0)

// ---- K2: SINGLE-PASS em-in-registers pre-pass. 512 blocks x 512 threads.
// [R7-verified: passed; R10-verified] — unchanged.
// R11 lesson (journal): fusing em into fhmm at __launch_bounds__(512,4)
// capped VGPR at 64 vs ~250 needed -> 753MB scratch traffic, 2x regression.
// A fused retry must use (512,1) for the 256-VGPR budget.
__global__ __launch_bounds__(512, 2)
void emP_kernel(const int* __restrict__ x,
                const float* __restrict__ lam1,
                const float* __restrict__ lam2,
                const float* __restrict__ lam3,
                ushort* __restrict__ P,
                float* __restrict__ SumAuxArr,
                float* __restrict__ out) {
    __shared__ float wmx[EROWS][8];
    __shared__ float DemS[EROWS];
    __shared__ float lgtbl[32];
    __shared__ __align__(16) float xfs[EROWS * MDIM];   // 512 floats
    __shared__ float lgred;
    const int tid = threadIdx.x, lane = tid & 63, wv = tid >> 6;
    const int q = lane >> 4, nn = lane & 15;
    const int d2 = 2 * wv + (nn >> 3);
    const int d3 = nn & 7;

    if (tid < 32) lgtbl[tid] = lgammaf((float)tid + 1.0f);
    if (tid == 0) lgred = 0.f;

    float llc[4][16], ls[4];
    #pragma unroll
    for (int j = 0; j < 4; ++j) {
        const int d1 = 4 * q + j;
        float sum = 0.f;
        #pragma unroll
        for (int m = 0; m < 16; ++m) {
            float la = lam1[d1 * 16 + m] + lam2[d2 * 16 + m] + lam3[d3 * 16 + m];
            sum += la;
            llc[j][m] = __logf(la);
        }
        ls[j] = sum;
    }

    const int t0 = blockIdx.x * EROWS;
    const int xv = x[t0 * MDIM + tid];
    xfs[tid] = (float)xv;
    __syncthreads();   // lgtbl + lgred + xfs ready
    {
        double lg = (double)lgtbl[xv & 31];
        lg = waveSumD(lg);
        if (lane == 0) atomicAdd(&lgred, (float)lg);
    }

    // ---- pass 1: em (kept in registers) + per-row wave maxima ----
    float em[EROWS][4];
    #pragma unroll
    for (int ti = 0; ti < EROWS; ++ti) {
        float xr[16];
        *(float4*)&xr[0]  = *(const float4*)&xfs[ti * 16 + 0];
        *(float4*)&xr[4]  = *(const float4*)&xfs[ti * 16 + 4];
        *(float4*)&xr[8]  = *(const float4*)&xfs[ti * 16 + 8];
        *(float4*)&xr[12] = *(const float4*)&xfs[ti * 16 + 12];
        float vm = -3.4e38f;
        #pragma unroll
        for (int j = 0; j < 4; ++j) {
            float d = 0.f;
            #pragma unroll
            for (int m = 0; m < 16; ++m) d = fmaf(xr[m], llc[j][m], d);
            em[ti][j] = d - ls[j];
            vm = fmaxf(vm, em[ti][j]);
        }
        vm = waveMax64(vm);
        if (lane == 0) wmx[ti][wv] = vm;     // wave-owned column, no race
    }
    __syncthreads();
    if (tid < 32) {
        float m = wmx[tid][0];
        #pragma unroll
        for (int i = 1; i < 8; ++i) m = fmaxf(m, wmx[tid][i]);
        DemS[tid] = m;
    }
    __syncthreads();

    // ---- pass 2: exp from registers, pack, streamed stores (no barriers) ----
    #pragma unroll
    for (int ti = 0; ti < EROWS; ++ti) {
        const float Dem = DemS[ti];
        uint2 w;
        w.x = pkbf(__expf(em[ti][0] - Dem), __expf(em[ti][1] - Dem));
        w.y = pkbf(__expf(em[ti][2] - Dem), __expf(em[ti][3] - Dem));
        *(uint2*)(P + (size_t)(t0 + ti) * SD + tid * 4) = w;
    }

    if (tid == 0) {
        double sumD = 0.0;
        #pragma unroll
        for (int i = 0; i < EROWS; ++i) sumD += (double)DemS[i];
        SumAuxArr[blockIdx.x] = (float)sumD - lgred;
        if (blockIdx.x == 0) out[0] = 0.f;
    }
}

// ---- K3: TWO-CHUNK interleaved forward recurrence. grid = CHKB(512) x 512.
// [R10-verified structure, passed absmax 0.0] — only change: WUP 16->8
// (NS 31->23): tA0 = 32b-WUP, tB0 = 32b+CLEN-WUP (both even, parity kept),
// guards unchanged (s > WUP <=> t > own bAcc).
__global__ __launch_bounds__(512, 4)
void fhmm_chunk_kernel(const ushort* __restrict__ P,
                       const float* __restrict__ SumAuxArr,
                       const float* __restrict__ logA1,
                       const float* __restrict__ logA2,
                       const float* __restrict__ logA3,
                       const float* __restrict__ logpi1,
                       const float* __restrict__ logpi2,
                       const float* __restrict__ logpi3,
                       float* __restrict__ out)
{
    __shared__ __align__(16) short c1bA[2 * 2048];  // chunk A parity double buffer
    __shared__ __align__(16) short c1bB[2 * 2048];  // chunk B parity double buffer
    __shared__ float wmAA[8], wmAB[8];              // odd steps write, even read
    __shared__ float sred[8];
    __shared__ float saux8[8];

    const int tid  = threadIdx.x;
    const int lane = tid & 63;
    const int wv   = tid >> 6;
    const int q    = lane >> 4;
    const int ml   = lane & 15;

    const int b   = blockIdx.x;
    // chunk A = 2b (owns (32b, 32b+16]), warm-start at 32b-WUP (b=0: exact at 0)
    // chunk B = 2b+1 (owns (32b+16, 32b+32]), warm-start at 32b+CLEN-WUP
    const int tA0 = (b == 0) ? 0 : 32 * b - WUP;
    const int tB0 = 32 * b + (CLEN - WUP);

    // S1 constants (K=16): B[k=p1=4q+j][n=d1'=ml] = exp(logA1[ml][4q+j])
    short4v bA1k;
    #pragma unroll
    for (int j = 0; j < 4; ++j)
        bA1k[j] = f2bfs(__expf(logA1[ml * 16 + 4 * q + j]));

    // S23 constants, 4 K-chunks: k' = 32jc + 8q + i -> p2 = 4jc+q, p3 = i
    const int d2p = 2 * wv + (ml >> 3);
    const int d3p = ml & 7;
    short8 bK[4];
    #pragma unroll
    for (int jc = 0; jc < 4; ++jc)
        #pragma unroll
        for (int i = 0; i < 8; ++i)
            bK[jc][i] = f2bfs(__expf(logA2[d2p * 16 + 4 * jc + q] + logA3[d3p * 8 + i]));

    // S1 D write offset  [R9/R10-verified]
    const int oS1w = ml * 128 + ((((2 * wv + (q >> 1)) ^ ml) & 15) << 3) + 4 * (q & 1);
    // S23 A-frag offsets [R9/R10-verified]
    int o23[4];
    #pragma unroll
    for (int jc = 0; jc < 4; ++jc)
        o23[jc] = ml * 128 + ((((4 * jc + q) ^ ml) & 15) << 3);

    // block 0: reduce the 512 per-block emission partials (consumed in tail)
    if (b == 0) {
        float sx = waveSumF(SumAuxArr[tid]);
        if (lane == 0) saux8[wv] = sx;
    }

    // ---- init both chunks ----
    double OFF = 0.0;     // combined A+B offset (tid0 only meaningful)
    float nuA[4], nuB[4];
    {
        uintx2 p0 = *(const uintx2*)(P + (size_t)tA0 * SD + tid * 4);
        if (b == 0) {   // exact: beta_0 = P_0 * pi
            float lp23 = logpi2[d2p] + logpi3[d3p];
            nuA[0] = bfl(p0.x) * __expf(logpi1[4 * q + 0] + lp23);
            nuA[1] = bfh(p0.x) * __expf(logpi1[4 * q + 1] + lp23);
            nuA[2] = bfl(p0.y) * __expf(logpi1[4 * q + 2] + lp23);
            nuA[3] = bfh(p0.y) * __expf(logpi1[4 * q + 3] + lp23);
        } else {
            nuA[0] = bfl(p0.x); nuA[1] = bfh(p0.x);
            nuA[2] = bfl(p0.y); nuA[3] = bfh(p0.y);
        }
    }
    {
        uintx2 p0 = *(const uintx2*)(P + (size_t)tB0 * SD + tid * 4);
        nuB[0] = bfl(p0.x); nuB[1] = bfh(p0.x);
        nuB[2] = bfl(p0.y); nuB[3] = bfh(p0.y);
    }

    // 2-deep P prefetch per chunk
    uintx2 PbA0 = *(const uintx2*)(P + (size_t)(tA0 + 1) * SD + tid * 4);
    uintx2 PbA1 = *(const uintx2*)(P + (size_t)(tA0 + 2) * SD + tid * 4);
    uintx2 PbB0 = *(const uintx2*)(P + (size_t)(tB0 + 1) * SD + tid * 4);
    uintx2 PbB1 = *(const uintx2*)(P + (size_t)(tB0 + 2) * SD + tid * 4);

// One SUPER-step: both chunks' step s, ONE barrier. RESC compile-time;
// ACCFA/ACCFB runtime-uniform accumulate guards.
#define SSTEP(S, RESC, ACCFA, ACCFB)                                            \
{                                                                               \
    const int par = (S) & 1;    /* tA0,tB0 even -> t parity == s parity */      \
    short* cAq = c1bA + (par << 11);                                            \
    short* cBq = c1bB + (par << 11);                                            \
    {   /* Stage 1, both chunks, from registers */                              \
        short4v afA = pk4(nuA[0], nuA[1], nuA[2], nuA[3]);                      \
        short4v afB = pk4(nuB[0], nuB[1], nuB[2], nuB[3]);                      \
        floatx4 sA = {0.f, 0.f, 0.f, 0.f};                                      \
        floatx4 sB = {0.f, 0.f, 0.f, 0.f};                                      \
        sA = MFMA16(afA, bA1k, sA);                                             \
        sB = MFMA16(afB, bA1k, sB);                                             \
        ((uintx2*)(cAq + oS1w))[0] = (uintx2){pkbf(sA[0], sA[1]), pkbf(sA[2], sA[3])}; \
        ((uintx2*)(cBq + oS1w))[0] = (uintx2){pkbf(sB[0], sB[1]), pkbf(sB[2], sB[3])}; \
    }                                                                           \
    __syncthreads();                                                            \
    const int tnA = (tA0 + (S) + 2 < TMAX) ? tA0 + (S) + 2 : TMAX - 1;          \
    const int tnB = (tB0 + (S) + 2 < TMAX) ? tB0 + (S) + 2 : TMAX - 1;          \
    uintx2 PbA2 = *(const uintx2*)(P + (size_t)tnA * SD + tid * 4);             \
    uintx2 PbB2 = *(const uintx2*)(P + (size_t)tnB * SD + tid * 4);             \
    float invA = 1.f, invB = 1.f;                                               \
    if (RESC) {                                                                 \
        float mpA = waveMax64(wmAA[lane & 7]);                                  \
        float mpB = waveMax64(wmAB[lane & 7]);                                  \
        float mgA = fmaxf(mpA, 1e-30f);                                         \
        float mgB = fmaxf(mpB, 1e-30f);                                         \
        invA = __builtin_amdgcn_rcpf(mgA);                                      \
        invB = __builtin_amdgcn_rcpf(mgB);                                      \
        if (tid == 0) {                                                         \
            if (ACCFA) OFF += (double)__logf(mgA);                              \
            if (ACCFB) OFF += (double)__logf(mgB);                              \
        }                                                                       \
    }                                                                           \
    {   /* Stage 2+3, both chunks: issue all 8 reads, then 8 MFMAs */           \
        short8 fA0 = *(const short8*)(cAq + o23[0]);                            \
        short8 fA1 = *(const short8*)(cAq + o23[1]);                            \
        short8 fA2 = *(const short8*)(cAq + o23[2]);                            \
        short8 fA3 = *(const short8*)(cAq + o23[3]);                            \
        short8 fB0 = *(const short8*)(cBq + o23[0]);                            \
        short8 fB1 = *(const short8*)(cBq + o23[1]);                            \
        short8 fB2 = *(const short8*)(cBq + o23[2]);                            \
        short8 fB3 = *(const short8*)(cBq + o23[3]);                            \
        floatx4 aA0 = {0.f, 0.f, 0.f, 0.f};                                     \
        floatx4 aA1 = {0.f, 0.f, 0.f, 0.f};                                     \
        floatx4 aB0 = {0.f, 0.f, 0.f, 0.f};                                     \
        floatx4 aB1 = {0.f, 0.f, 0.f, 0.f};                                     \
        aA0 = MFMA32(fA0, bK[0], aA0);  aB0 = MFMA32(fB0, bK[0], aB0);          \
        aA1 = MFMA32(fA1, bK[1], aA1);  aB1 = MFMA32(fB1, bK[1], aB1);          \
        aA0 = MFMA32(fA2, bK[2], aA0);  aB0 = MFMA32(fB2, bK[2], aB0);          \
        aA1 = MFMA32(fA3, bK[3], aA1);  aB1 = MFMA32(fB3, bK[3], aB1);          \
        floatx4 accA = aA0 + aA1;                                               \
        floatx4 accB = aB0 + aB1;                                               \
        if (RESC) {                                                             \
            nuA[0] = bfl(PbA0.x) * accA[0] * invA;                              \
            nuA[1] = bfh(PbA0.x) * accA[1] * invA;                              \
            nuA[2] = bfl(PbA0.y) * accA[2] * invA;                              \
            nuA[3] = bfh(PbA0.y) * accA[3] * invA;                              \
            nuB[0] = bfl(PbB0.x) * accB[0] * invB;                              \
            nuB[1] = bfh(PbB0.x) * accB[1] * invB;                              \
            nuB[2] = bfl(PbB0.y) * accB[2] * invB;                              \
            nuB[3] = bfh(PbB0.y) * accB[3] * invB;                              \
        } else {                                                                \
            nuA[0] = bfl(PbA0.x) * accA[0];                                     \
            nuA[1] = bfh(PbA0.x) * accA[1];                                     \
            nuA[2] = bfl(PbA0.y) * accA[2];                                     \
            nuA[3] = bfh(PbA0.y) * accA[3];                                     \
            nuB[0] = bfl(PbB0.x) * accB[0];                                     \
            nuB[1] = bfh(PbB0.x) * accB[1];                                     \
            nuB[2] = bfl(PbB0.y) * accB[2];                                     \
            nuB[3] = bfh(PbB0.y) * accB[3];                                     \
            float waA = waveMax64(fmaxf(fmaxf(nuA[0], nuA[1]), fmaxf(nuA[2], nuA[3]))); \
            float waB = waveMax64(fmaxf(fmaxf(nuB[0], nuB[1]), fmaxf(nuB[2], nuB[3]))); \
            if (lane == 0) { wmAA[wv] = waA; wmAB[wv] = waB; }                  \
        }                                                                       \
    }                                                                           \
    PbA0 = PbA1; PbA1 = PbA2; PbB0 = PbB1; PbB1 = PbB2;                         \
}

    // s = 1 .. NS(=23); first/last odd (non-RESC), RESC on even s.
    // accfA: chunk 0 accumulates always; others when s > WUP. accfB: s > WUP.
    SSTEP(1, false, false, false);
    for (int s = 2; s < NS; s += 2) {
        const bool accfA = (b == 0) || (s > WUP);
        const bool accfB = (s > WUP);
        SSTEP(s, true, accfA, accfB);
        SSTEP(s + 1, false, false, false);
    }
#undef SSTEP

    __syncthreads();

    if (b == CHKB - 1) {     // chunk B here is the LAST chunk: sum path
        float su = waveSumF(nuB[0] + nuB[1] + nuB[2] + nuB[3]);
        if (lane == 0) sred[wv] = su;
        __syncthreads();
        if (tid == 0) {
            float mpA = wmAA[0];
            #pragma unroll
            for (int i = 1; i < 8; ++i) mpA = fmaxf(mpA, wmAA[i]);
            OFF += (double)__logf(fmaxf(mpA, 1e-30f));
            float tot = 0.f;
            #pragma unroll
            for (int i = 0; i < 8; ++i) tot += sred[i];
            OFF += (double)__logf(tot);
            atomicAdd(out, (float)OFF);
        }
    } else {
        if (tid == 0) {
            float mpA = wmAA[0], mpB = wmAB[0];
            #pragma unroll
            for (int i = 1; i < 8; ++i) {
                mpA = fmaxf(mpA, wmAA[i]);
                mpB = fmaxf(mpB, wmAB[i]);
            }
            OFF += (double)__logf(fmaxf(mpA, 1e-30f));
            OFF += (double)__logf(fmaxf(mpB, 1e-30f));
            if (b == 0) {
                float sa = 0.f;
                #pragma unroll
                for (int i = 0; i < 8; ++i) sa += saux8[i];
                OFF += (double)sa;
            }
            atomicAdd(out, (float)OFF);
        }
    }
}

extern "C" void kernel_launch(void* const* d_in, const int* in_sizes, int n_in,
                              void* d_out, int out_size, void* d_ws, size_t ws_size,
                              hipStream_t stream) {
    const int*   x      = (const int*)  d_in[0];
    const float* lam1   = (const float*)d_in[1];
    const float* lam2   = (const float*)d_in[2];
    const float* lam3   = (const float*)d_in[3];
    const float* logA1  = (const float*)d_in[4];
    const float* logA2  = (const float*)d_in[5];
    const float* logA3  = (const float*)d_in[6];
    const float* logpi1 = (const float*)d_in[7];
    const float* logpi2 = (const float*)d_in[8];
    const float* logpi3 = (const float*)d_in[9];
    float* out = (float*)d_out;

    // ws: [SumAuxArr: 512 floats (2KB), pad to 4KB] [P_perm: TMAX*2048*2B = 64MB]
    float*  SumAuxArr = (float*)d_ws;
    ushort* P         = (ushort*)((char*)d_ws + 4096);

    // no memsets: out zeroed by emP block 0; SumAuxArr fully overwritten by
    // emP plain stores (one per block, 512 blocks == array size).
    emP_kernel <<<dim3(TMAX / EROWS), dim3(512), 0, stream>>>(
        x, lam1, lam2, lam3, P, SumAuxArr, out);
    fhmm_chunk_kernel<<<dim3(CHKB), dim3(512), 0, stream>>>(
        P, SumAuxArr, logA1, logA2, logA3, logpi1, logpi2, logpi3, out);
}

// Round 14
// 134.376 us; speedup vs baseline: 2.6996x; 1.0826x over previous
//
#include <hip/hip_runtime.h>
#include <math.h>

#define TMAX 16384
#define MDIM 16
#define SD   2048
#define CLEN 16      // steps per chunk
#define WUP  4       // warmup steps (8 verified R13 absmax 0.0; 4 -> err << bf16 ULP)
#define CHKB 512     // fhmm blocks; each runs TWO chunks (cA=2b, cB=2b+1)
#define NS   (CLEN + WUP - 1)   // 19 steps per chunk (odd; s=1 prologue + 9 pairs)

typedef unsigned int  uint;
typedef unsigned short ushort;
typedef __attribute__((ext_vector_type(8))) short short8;
typedef __attribute__((ext_vector_type(4))) short short4v;
typedef __attribute__((ext_vector_type(4))) float floatx4;
typedef __attribute__((ext_vector_type(2))) uint uintx2;

// ---- DPP-based full-wave (64-lane) max ----
template<int CTRL>
__device__ __forceinline__ float fmax_dpp(float v) {
    int o = __builtin_amdgcn_update_dpp(__float_as_int(v), __float_as_int(v),
                                        CTRL, 0xf, 0xf, false);
    return fmaxf(v, __int_as_float(o));
}
__device__ __forceinline__ float waveMax64(float v) {
    v = fmax_dpp<0x111>(v);
    v = fmax_dpp<0x112>(v);
    v = fmax_dpp<0x114>(v);
    v = fmax_dpp<0x118>(v);
    v = fmax_dpp<0x142>(v);
    v = fmax_dpp<0x143>(v);
    return __int_as_float(__builtin_amdgcn_readlane(__float_as_int(v), 63));
}
__device__ __forceinline__ float waveSumF(float v) {
    #pragma unroll
    for (int o = 32; o > 0; o >>= 1) v += __shfl_xor(v, o, 64);
    return v;
}
__device__ __forceinline__ double waveSumD(double v) {
    #pragma unroll
    for (int o = 32; o > 0; o >>= 1) v += __shfl_xor(v, o, 64);
    return v;
}

// bf16 helpers (RNE emulation — bit-exact, harness-proven)
__device__ __forceinline__ short f2bfs(float f) {
    uint u = __float_as_uint(f);
    return (short)((u + 0x7FFFu + ((u >> 16) & 1u)) >> 16);
}
__device__ __forceinline__ uint pkbf(float a, float b) {
    uint ua = __float_as_uint(a), ub = __float_as_uint(b);
    ua = (ua + 0x7FFFu + ((ua >> 16) & 1u)) >> 16;
    ub = (ub + 0x7FFFu + ((ub >> 16) & 1u)) & 0xFFFF0000u;
    return ua | ub;
}
__device__ __forceinline__ short4v pk4(float a, float b, float c, float d) {
    short4v r;
    r[0] = f2bfs(a); r[1] = f2bfs(b); r[2] = f2bfs(c); r[3] = f2bfs(d);
    return r;
}
__device__ __forceinline__ float bfl(uint u) { return __uint_as_float(u << 16); }
__device__ __forceinline__ float bfh(uint u) { return __uint_as_float(u & 0xFFFF0000u); }

// K=16 bf16 MFMA
#if __has_builtin(__builtin_amdgcn_mfma_f32_16x16x16bf16_1k)
#define MFMA16(a, b, c) __builtin_amdgcn_mfma_f32_16x16x16bf16_1k(a, b, c, 0, 0, 0)
#else
__device__ __forceinline__ floatx4 mfma16_asm(short4v a, short4v b, floatx4 c) {
    asm volatile("v_mfma_f32_16x16x16_bf16 %0, %1, %2, %0\n\t"
                 "s_nop 7\n\ts_nop 7"
                 : "+v"(c) : "v"(a), "v"(b));
    return c;
}
#define MFMA16(a, b, c) mfma16_asm(a, b, c)
#endif
#define MFMA32(a, b, c) __builtin_amdgcn_mfma_f32_16x16x32_bf16(a, b, c, 0, 0, 0)

// ---- K2: MFMA emission pre-pass. 512 blocks x 512 threads x 32 t-rows.
// R13 post-mortem: emP was VALU-inst-count bound (31us of 45 = issue of 2048
// fmac/thread). This version computes em = x @ llc^T via mfma_16x16x16_bf16:
// per wave 16 s-tiles x 2 t-tiles x 2 (hi/lo llc split -> f32-quality), -ls
// folded into C. Fragment conventions = fhmm-S1-verified: A[row=l&15][k=
// (l>>4)*4+e], B[k][col=l&15], D col=l&15,row=(l>>4)*4+reg.
// Output bounced through 64KB LDS Pstg into the VERIFIED slot order
// o(s) = (64*((s>>4)&7) + 16*((s>>7)>>2) + (s&15))*4 + ((s>>7)&3),
// flushed 16B/lane coalesced -> P layout bit-compatible with fhmm.
// __launch_bounds__(512,1): 256-VGPR budget for em4[2][16] (R11 lesson).
__global__ __launch_bounds__(512, 1)
void emP_kernel(const int* __restrict__ x,
                const float* __restrict__ lam1,
                const float* __restrict__ lam2,
                const float* __restrict__ lam3,
                ushort* __restrict__ P,
                float* __restrict__ SumAuxArr,
                float* __restrict__ out) {
    __shared__ __align__(16) ushort Pstg[16 * 2048];   // 64 KB, reused per half
    __shared__ float wmx[32][8];
    __shared__ float DemS[32];
    __shared__ float lgtbl[32];
    __shared__ float lgred;

    const int tid = threadIdx.x, lane = tid & 63, wv = tid >> 6;
    const int c = lane & 15;         // column within tile (s low bits / t-row)
    const int g = lane >> 4;         // k-group / row-group
    const int t0 = blockIdx.x * 32;

    if (tid < 32) lgtbl[tid] = lgammaf((float)tid + 1.0f);
    if (tid == 0) lgred = 0.f;

    // A fragments (x block, exact in bf16): aF[h] = x[t0+h*16+c][g*4 .. g*4+3]
    short4v aF[2];
    #pragma unroll
    for (int h = 0; h < 2; ++h) {
        int4 xi = *(const int4*)&x[(t0 + h * 16 + c) * MDIM + g * 4];
        aF[h] = pk4((float)xi.x, (float)xi.y, (float)xi.z, (float)xi.w);
    }
    // lam rows for this lane's m-quad: d3 = c&7 fixed; d1 in {2wv, 2wv+1}
    const float4 l3  = *(const float4*)&lam3[(c & 7) * MDIM + g * 4];
    const float4 l1a = *(const float4*)&lam1[(2 * wv) * MDIM + g * 4];
    const float4 l1b = *(const float4*)&lam1[(2 * wv + 1) * MDIM + g * 4];

    __syncthreads();   // lgtbl + lgred ready
    {
        int xv = x[t0 * MDIM + tid];
        double lg = (double)lgtbl[xv & 31];
        lg = waveSumD(lg);
        if (lane == 0) atomicAdd(&lgred, (float)lg);
    }

    // ---- MFMA phase: em4[h][st] = x-tile(h) @ llc-tile(st)^T - ls ----
    // wave wv covers s in [wv*256, wv*256+256): s = wv*256 + st*16 + c
    floatx4 em4[2][16];
    #pragma unroll
    for (int st = 0; st < 16; ++st) {
        const int d2 = ((wv << 5) + (st << 1) + (c >> 3)) & 15;
        const float4 l2 = *(const float4*)&lam2[d2 * MDIM + g * 4];
        const float4 l1 = (st < 8) ? l1a : l1b;
        const float la0 = l1.x + l2.x + l3.x;
        const float la1 = l1.y + l2.y + l3.y;
        const float la2 = l1.z + l2.z + l3.z;
        const float la3 = l1.w + l2.w + l3.w;
        // full ls[s]: partial over this lane's m-quad, fold across g (xor 16,32)
        float lsp = la0 + la1 + la2 + la3;
        lsp += __shfl_xor(lsp, 16, 64);
        lsp += __shfl_xor(lsp, 32, 64);
        // llc hi/lo bf16 split (f32-quality dot)
        const float ll0 = __logf(la0), ll1 = __logf(la1);
        const float ll2 = __logf(la2), ll3 = __logf(la3);
        short4v bh, bl;
        bh[0] = f2bfs(ll0); bl[0] = f2bfs(ll0 - bfl((uint)(ushort)bh[0]));
        bh[1] = f2bfs(ll1); bl[1] = f2bfs(ll1 - bfl((uint)(ushort)bh[1]));
        bh[2] = f2bfs(ll2); bl[2] = f2bfs(ll2 - bfl((uint)(ushort)bh[2]));
        bh[3] = f2bfs(ll3); bl[3] = f2bfs(ll3 - bfl((uint)(ushort)bh[3]));
        #pragma unroll
        for (int h = 0; h < 2; ++h) {
            floatx4 acc = {-lsp, -lsp, -lsp, -lsp};
            acc = MFMA16(aF[h], bh, acc);
            acc = MFMA16(aF[h], bl, acc);
            em4[h][st] = acc;
        }
    }

    // ---- Dem: per t-row max over all s. lane reg r -> t = h*16 + g*4 + r ----
    #pragma unroll
    for (int h = 0; h < 2; ++h)
        #pragma unroll
        for (int r = 0; r < 4; ++r) {
            float m = em4[h][0][r];
            #pragma unroll
            for (int st = 1; st < 16; ++st) m = fmaxf(m, em4[h][st][r]);
            m = fmaxf(m, __shfl_xor(m, 1, 64));
            m = fmaxf(m, __shfl_xor(m, 2, 64));
            m = fmaxf(m, __shfl_xor(m, 4, 64));
            m = fmaxf(m, __shfl_xor(m, 8, 64));
            if (c == 0) wmx[h * 16 + g * 4 + r][wv] = m;
        }
    __syncthreads();
    if (tid < 32) {
        float m = wmx[tid][0];
        #pragma unroll
        for (int i = 1; i < 8; ++i) m = fmaxf(m, wmx[tid][i]);
        DemS[tid] = m;
    }
    __syncthreads();

    // ---- output: exp, slot-permute via Pstg, coalesced flush; per t-half ----
    #pragma unroll
    for (int h = 0; h < 2; ++h) {
        if (h == 1) __syncthreads();      // Pstg reuse: prior flush reads done
        float dd[4];
        #pragma unroll
        for (int r = 0; r < 4; ++r) dd[r] = DemS[h * 16 + g * 4 + r];
        #pragma unroll
        for (int st = 0; st < 16; ++st) {
            const int d1 = 2 * wv + (st >> 3);
            const int oidx = (64 * (st & 7) + 16 * (d1 >> 2) + c) * 4 + (d1 & 3);
            #pragma unroll
            for (int r = 0; r < 4; ++r) {
                float p = __expf(em4[h][st][r] - dd[r]);
                Pstg[(g * 4 + r) * 2048 + oidx] = (ushort)f2bfs(p);
            }
        }
        __syncthreads();                  // Pstg complete
        #pragma unroll
        for (int it = 0; it < 8; ++it) {
            const int flat = it * 512 + tid;
            uint4 v = ((const uint4*)Pstg)[flat];
            *(uint4*)(P + (size_t)(t0 + h * 16) * SD + flat * 8) = v;
        }
    }

    if (tid == 0) {
        double sumD = 0.0;
        #pragma unroll
        for (int i = 0; i < 32; ++i) sumD += (double)DemS[i];
        SumAuxArr[blockIdx.x] = (float)sumD - lgred;
        if (blockIdx.x == 0) out[0] = 0.f;
    }
}

// ---- K3: TWO-CHUNK interleaved forward recurrence. grid = CHKB(512) x 512.
// [R10/R13-verified structure, absmax 0.0] — only change: WUP 8->4 (NS 23->19).
__global__ __launch_bounds__(512, 4)
void fhmm_chunk_kernel(const ushort* __restrict__ P,
                       const float* __restrict__ SumAuxArr,
                       const float* __restrict__ logA1,
                       const float* __restrict__ logA2,
                       const float* __restrict__ logA3,
                       const float* __restrict__ logpi1,
                       const float* __restrict__ logpi2,
                       const float* __restrict__ logpi3,
                       float* __restrict__ out)
{
    __shared__ __align__(16) short c1bA[2 * 2048];  // chunk A parity double buffer
    __shared__ __align__(16) short c1bB[2 * 2048];  // chunk B parity double buffer
    __shared__ float wmAA[8], wmAB[8];              // odd steps write, even read
    __shared__ float sred[8];
    __shared__ float saux8[8];

    const int tid  = threadIdx.x;
    const int lane = tid & 63;
    const int wv   = tid >> 6;
    const int q    = lane >> 4;
    const int ml   = lane & 15;

    const int b   = blockIdx.x;
    const int tA0 = (b == 0) ? 0 : 32 * b - WUP;
    const int tB0 = 32 * b + (CLEN - WUP);

    // S1 constants (K=16): B[k=p1=4q+j][n=d1'=ml] = exp(logA1[ml][4q+j])
    short4v bA1k;
    #pragma unroll
    for (int j = 0; j < 4; ++j)
        bA1k[j] = f2bfs(__expf(logA1[ml * 16 + 4 * q + j]));

    // S23 constants, 4 K-chunks: k' = 32jc + 8q + i -> p2 = 4jc+q, p3 = i
    const int d2p = 2 * wv + (ml >> 3);
    const int d3p = ml & 7;
    short8 bK[4];
    #pragma unroll
    for (int jc = 0; jc < 4; ++jc)
        #pragma unroll
        for (int i = 0; i < 8; ++i)
            bK[jc][i] = f2bfs(__expf(logA2[d2p * 16 + 4 * jc + q] + logA3[d3p * 8 + i]));

    // S1 D write offset  [R9/R10-verified]
    const int oS1w = ml * 128 + ((((2 * wv + (q >> 1)) ^ ml) & 15) << 3) + 4 * (q & 1);
    // S23 A-frag offsets [R9/R10-verified]
    int o23[4];
    #pragma unroll
    for (int jc = 0; jc < 4; ++jc)
        o23[jc] = ml * 128 + ((((4 * jc + q) ^ ml) & 15) << 3);

    // block 0: reduce the 512 per-block emission partials (consumed in tail)
    if (b == 0) {
        float sx = waveSumF(SumAuxArr[tid]);
        if (lane == 0) saux8[wv] = sx;
    }

    // ---- init both chunks ----
    double OFF = 0.0;
    float nuA[4], nuB[4];
    {
        uintx2 p0 = *(const uintx2*)(P + (size_t)tA0 * SD + tid * 4);
        if (b == 0) {   // exact: beta_0 = P_0 * pi
            float lp23 = logpi2[d2p] + logpi3[d3p];
            nuA[0] = bfl(p0.x) * __expf(logpi1[4 * q + 0] + lp23);
            nuA[1] = bfh(p0.x) * __expf(logpi1[4 * q + 1] + lp23);
            nuA[2] = bfl(p0.y) * __expf(logpi1[4 * q + 2] + lp23);
            nuA[3] = bfh(p0.y) * __expf(logpi1[4 * q + 3] + lp23);
        } else {
            nuA[0] = bfl(p0.x); nuA[1] = bfh(p0.x);
            nuA[2] = bfl(p0.y); nuA[3] = bfh(p0.y);
        }
    }
    {
        uintx2 p0 = *(const uintx2*)(P + (size_t)tB0 * SD + tid * 4);
        nuB[0] = bfl(p0.x); nuB[1] = bfh(p0.x);
        nuB[2] = bfl(p0.y); nuB[3] = bfh(p0.y);
    }

    // 2-deep P prefetch per chunk
    uintx2 PbA0 = *(const uintx2*)(P + (size_t)(tA0 + 1) * SD + tid * 4);
    uintx2 PbA1 = *(const uintx2*)(P + (size_t)(tA0 + 2) * SD + tid * 4);
    uintx2 PbB0 = *(const uintx2*)(P + (size_t)(tB0 + 1) * SD + tid * 4);
    uintx2 PbB1 = *(const uintx2*)(P + (size_t)(tB0 + 2) * SD + tid * 4);

#define SSTEP(S, RESC, ACCFA, ACCFB)                                            \
{                                                                               \
    const int par = (S) & 1;                                                    \
    short* cAq = c1bA + (par << 11);                                            \
    short* cBq = c1bB + (par << 11);                                            \
    {   /* Stage 1, both chunks, from registers */                              \
        short4v afA = pk4(nuA[0], nuA[1], nuA[2], nuA[3]);                      \
        short4v afB = pk4(nuB[0], nuB[1], nuB[2], nuB[3]);                      \
        floatx4 sA = {0.f, 0.f, 0.f, 0.f};                                      \
        floatx4 sB = {0.f, 0.f, 0.f, 0.f};                                      \
        sA = MFMA16(afA, bA1k, sA);                                             \
        sB = MFMA16(afB, bA1k, sB);                                             \
        ((uintx2*)(cAq + oS1w))[0] = (uintx2){pkbf(sA[0], sA[1]), pkbf(sA[2], sA[3])}; \
        ((uintx2*)(cBq + oS1w))[0] = (uintx2){pkbf(sB[0], sB[1]), pkbf(sB[2], sB[3])}; \
    }                                                                           \
    __syncthreads();                                                            \
    const int tnA = (tA0 + (S) + 2 < TMAX) ? tA0 + (S) + 2 : TMAX - 1;          \
    const int tnB = (tB0 + (S) + 2 < TMAX) ? tB0 + (S) + 2 : TMAX - 1;          \
    uintx2 PbA2 = *(const uintx2*)(P + (size_t)tnA * SD + tid * 4);             \
    uintx2 PbB2 = *(const uintx2*)(P + (size_t)tnB * SD + tid * 4);             \
    float invA = 1.f, invB = 1.f;                                               \
    if (RESC) {                                                                 \
        float mpA = waveMax64(wmAA[lane & 7]);                                  \
        float mpB = waveMax64(wmAB[lane & 7]);                                  \
        float mgA = fmaxf(mpA, 1e-30f);                                         \
        float mgB = fmaxf(mpB, 1e-30f);                                         \
        invA = __builtin_amdgcn_rcpf(mgA);                                      \
        invB = __builtin_amdgcn_rcpf(mgB);                                      \
        if (tid == 0) {                                                         \
            if (ACCFA) OFF += (double)__logf(mgA);                              \
            if (ACCFB) OFF += (double)__logf(mgB);                              \
        }                                                                       \
    }                                                                           \
    {   /* Stage 2+3, both chunks: issue all 8 reads, then 8 MFMAs */           \
        short8 fA0 = *(const short8*)(cAq + o23[0]);                            \
        short8 fA1 = *(const short8*)(cAq + o23[1]);                            \
        short8 fA2 = *(const short8*)(cAq + o23[2]);                            \
        short8 fA3 = *(const short8*)(cAq + o23[3]);                            \
        short8 fB0 = *(const short8*)(cBq + o23[0]);                            \
        short8 fB1 = *(const short8*)(cBq + o23[1]);                            \
        short8 fB2 = *(const short8*)(cBq + o23[2]);                            \
        short8 fB3 = *(const short8*)(cBq + o23[3]);                            \
        floatx4 aA0 = {0.f, 0.f, 0.f, 0.f};                                     \
        floatx4 aA1 = {0.f, 0.f, 0.f, 0.f};                                     \
        floatx4 aB0 = {0.f, 0.f, 0.f, 0.f};                                     \
        floatx4 aB1 = {0.f, 0.f, 0.f, 0.f};                                     \
        aA0 = MFMA32(fA0, bK[0], aA0);  aB0 = MFMA32(fB0, bK[0], aB0);          \
        aA1 = MFMA32(fA1, bK[1], aA1);  aB1 = MFMA32(fB1, bK[1], aB1);          \
        aA0 = MFMA32(fA2, bK[2], aA0);  aB0 = MFMA32(fB2, bK[2], aB0);          \
        aA1 = MFMA32(fA3, bK[3], aA1);  aB1 = MFMA32(fB3, bK[3], aB1);          \
        floatx4 accA = aA0 + aA1;                                               \
        floatx4 accB = aB0 + aB1;                                               \
        if (RESC) {                                                             \
            nuA[0] = bfl(PbA0.x) * accA[0] * invA;                              \
            nuA[1] = bfh(PbA0.x) * accA[1] * invA;                              \
            nuA[2] = bfl(PbA0.y) * accA[2] * invA;                              \
            nuA[3] = bfh(PbA0.y) * accA[3] * invA;                              \
            nuB[0] = bfl(PbB0.x) * accB[0] * invB;                              \
            nuB[1] = bfh(PbB0.x) * accB[1] * invB;                              \
            nuB[2] = bfl(PbB0.y) * accB[2] * invB;                              \
            nuB[3] = bfh(PbB0.y) * accB[3] * invB;                              \
        } else {                                                                \
            nuA[0] = bfl(PbA0.x) * accA[0];                                     \
            nuA[1] = bfh(PbA0.x) * accA[1];                                     \
            nuA[2] = bfl(PbA0.y) * accA[2];                                     \
            nuA[3] = bfh(PbA0.y) * accA[3];                                     \
            nuB[0] = bfl(PbB0.x) * accB[0];                                     \
            nuB[1] = bfh(PbB0.x) * accB[1];                                     \
            nuB[2] = bfl(PbB0.y) * accB[2];                                     \
            nuB[3] = bfh(PbB0.y) * accB[3];                                     \
            float waA = waveMax64(fmaxf(fmaxf(nuA[0], nuA[1]), fmaxf(nuA[2], nuA[3]))); \
            float waB = waveMax64(fmaxf(fmaxf(nuB[0], nuB[1]), fmaxf(nuB[2], nuB[3]))); \
            if (lane == 0) { wmAA[wv] = waA; wmAB[wv] = waB; }                  \
        }                                                                       \
    }                                                                           \
    PbA0 = PbA1; PbA1 = PbA2; PbB0 = PbB1; PbB1 = PbB2;                         \
}

    // s = 1 .. NS(=19); first/last odd (non-RESC), RESC on even s.
    SSTEP(1, false, false, false);
    for (int s = 2; s < NS; s += 2) {
        const bool accfA = (b == 0) || (s > WUP);
        const bool accfB = (s > WUP);
        SSTEP(s, true, accfA, accfB);
        SSTEP(s + 1, false, false, false);
    }
#undef SSTEP

    __syncthreads();

    if (b == CHKB - 1) {     // chunk B here is the LAST chunk: sum path
        float su = waveSumF(nuB[0] + nuB[1] + nuB[2] + nuB[3]);
        if (lane == 0) sred[wv] = su;
        __syncthreads();
        if (tid == 0) {
            float mpA = wmAA[0];
            #pragma unroll
            for (int i = 1; i < 8; ++i) mpA = fmaxf(mpA, wmAA[i]);
            OFF += (double)__logf(fmaxf(mpA, 1e-30f));
            float tot = 0.f;
            #pragma unroll
            for (int i = 0; i < 8; ++i) tot += sred[i];
            OFF += (double)__logf(tot);
            atomicAdd(out, (float)OFF);
        }
    } else {
        if (tid == 0) {
            float mpA = wmAA[0], mpB = wmAB[0];
            #pragma unroll
            for (int i = 1; i < 8; ++i) {
                mpA = fmaxf(mpA, wmAA[i]);
                mpB = fmaxf(mpB, wmAB[i]);
            }
            OFF += (double)__logf(fmaxf(mpA, 1e-30f));
            OFF += (double)__logf(fmaxf(mpB, 1e-30f));
            if (b == 0) {
                float sa = 0.f;
                #pragma unroll
                for (int i = 0; i < 8; ++i) sa += saux8[i];
                OFF += (double)sa;
            }
            atomicAdd(out, (float)OFF);
        }
    }
}

extern "C" void kernel_launch(void* const* d_in, const int* in_sizes, int n_in,
                              void* d_out, int out_size, void* d_ws, size_t ws_size,
                              hipStream_t stream) {
    const int*   x      = (const int*)  d_in[0];
    const float* lam1   = (const float*)d_in[1];
    const float* lam2   = (const float*)d_in[2];
    const float* lam3   = (const float*)d_in[3];
    const float* logA1  = (const float*)d_in[4];
    const float* logA2  = (const float*)d_in[5];
    const float* logA3  = (const float*)d_in[6];
    const float* logpi1 = (const float*)d_in[7];
    const float* logpi2 = (const float*)d_in[8];
    const float* logpi3 = (const float*)d_in[9];
    float* out = (float*)d_out;

    // ws: [SumAuxArr: 512 floats (2KB), pad to 4KB] [P_perm: TMAX*2048*2B = 64MB]
    float*  SumAuxArr = (float*)d_ws;
    ushort* P         = (ushort*)((char*)d_ws + 4096);

    // no memsets: out zeroed by emP block 0; SumAuxArr fully overwritten.
    emP_kernel <<<dim3(TMAX / 32), dim3(512), 0, stream>>>(
        x, lam1, lam2, lam3, P, SumAuxArr, out);
    fhmm_chunk_kernel<<<dim3(CHKB), dim3(512), 0, stream>>>(
        P, SumAuxArr, logA1, logA2, logA3, logpi1, logpi2, logpi3, out);
}

// Round 16
// 129.777 us; speedup vs baseline: 2.7953x; 1.0354x over previous
//
#include <hip/hip_runtime.h>
#include <math.h>

#define TMAX 16384
#define MDIM 16
#define SD   2048
#define CLEN 16      // steps per chunk
#define WUP  2       // warmup steps (32/16/8/4 all verified absmax 0.0; err << bf16 ULP)
#define CHKB 512     // fhmm blocks; each runs TWO chunks (cA=2b, cB=2b+1)
#define NS   (CLEN + WUP - 1)   // 17 steps per chunk (odd; s=1 prologue + 8 pairs)

typedef unsigned int  uint;
typedef unsigned short ushort;
typedef __attribute__((ext_vector_type(8))) short short8;
typedef __attribute__((ext_vector_type(4))) short short4v;
typedef __attribute__((ext_vector_type(4))) float floatx4;
typedef __attribute__((ext_vector_type(2))) uint uintx2;

// ---- DPP-based full-wave (64-lane) max ----
template<int CTRL>
__device__ __forceinline__ float fmax_dpp(float v) {
    int o = __builtin_amdgcn_update_dpp(__float_as_int(v), __float_as_int(v),
                                        CTRL, 0xf, 0xf, false);
    return fmaxf(v, __int_as_float(o));
}
__device__ __forceinline__ float waveMax64(float v) {
    v = fmax_dpp<0x111>(v);
    v = fmax_dpp<0x112>(v);
    v = fmax_dpp<0x114>(v);
    v = fmax_dpp<0x118>(v);
    v = fmax_dpp<0x142>(v);
    v = fmax_dpp<0x143>(v);
    return __int_as_float(__builtin_amdgcn_readlane(__float_as_int(v), 63));
}
__device__ __forceinline__ float waveSumF(float v) {
    #pragma unroll
    for (int o = 32; o > 0; o >>= 1) v += __shfl_xor(v, o, 64);
    return v;
}
__device__ __forceinline__ double waveSumD(double v) {
    #pragma unroll
    for (int o = 32; o > 0; o >>= 1) v += __shfl_xor(v, o, 64);
    return v;
}

// bf16 helpers (RNE emulation — bit-exact, harness-proven)
__device__ __forceinline__ short f2bfs(float f) {
    uint u = __float_as_uint(f);
    return (short)((u + 0x7FFFu + ((u >> 16) & 1u)) >> 16);
}
__device__ __forceinline__ uint pkbf(float a, float b) {
    uint ua = __float_as_uint(a), ub = __float_as_uint(b);
    ua = (ua + 0x7FFFu + ((ua >> 16) & 1u)) >> 16;
    ub = (ub + 0x7FFFu + ((ub >> 16) & 1u)) & 0xFFFF0000u;
    return ua | ub;
}
__device__ __forceinline__ short4v pk4(float a, float b, float c, float d) {
    short4v r;
    r[0] = f2bfs(a); r[1] = f2bfs(b); r[2] = f2bfs(c); r[3] = f2bfs(d);
    return r;
}
__device__ __forceinline__ float bfl(uint u) { return __uint_as_float(u << 16); }
__device__ __forceinline__ float bfh(uint u) { return __uint_as_float(u & 0xFFFF0000u); }

// K=16 bf16 MFMA
#if __has_builtin(__builtin_amdgcn_mfma_f32_16x16x16bf16_1k)
#define MFMA16(a, b, c) __builtin_amdgcn_mfma_f32_16x16x16bf16_1k(a, b, c, 0, 0, 0)
#else
__device__ __forceinline__ floatx4 mfma16_asm(short4v a, short4v b, floatx4 c) {
    asm volatile("v_mfma_f32_16x16x16_bf16 %0, %1, %2, %0\n\t"
                 "s_nop 7\n\ts_nop 7"
                 : "+v"(c) : "v"(a), "v"(b));
    return c;
}
#define MFMA16(a, b, c) mfma16_asm(a, b, c)
#endif
#define MFMA32(a, b, c) __builtin_amdgcn_mfma_f32_16x16x32_bf16(a, b, c, 0, 0, 0)

// ---- K2: MFMA emission pre-pass [R14-verified: passed, absmax 0.0].
// Only change this round: out-phase pairs (st, st+8) -> adjacent 2-aligned
// slots (d1 = 2wv, 2wv+1), packed with pkbf into ONE b32 LDS write
// (uintIdx = base*2 + (wv&1), base = 64*stp + 16*(wv>>1) + c) — halves the
// 128 scalar b16 LDS writes per thread.
__global__ __launch_bounds__(512, 1)
void emP_kernel(const int* __restrict__ x,
                const float* __restrict__ lam1,
                const float* __restrict__ lam2,
                const float* __restrict__ lam3,
                ushort* __restrict__ P,
                float* __restrict__ SumAuxArr,
                float* __restrict__ out) {
    __shared__ __align__(16) ushort Pstg[16 * 2048];   // 64 KB, reused per half
    __shared__ float wmx[32][8];
    __shared__ float DemS[32];
    __shared__ float lgtbl[32];
    __shared__ float lgred;

    uint* Pstg32 = (uint*)Pstg;
    const int tid = threadIdx.x, lane = tid & 63, wv = tid >> 6;
    const int c = lane & 15;         // column within tile (s low bits / t-row)
    const int g = lane >> 4;         // k-group / row-group
    const int t0 = blockIdx.x * 32;

    if (tid < 32) lgtbl[tid] = lgammaf((float)tid + 1.0f);
    if (tid == 0) lgred = 0.f;

    // A fragments (x block, exact in bf16): aF[h] = x[t0+h*16+c][g*4 .. g*4+3]
    short4v aF[2];
    #pragma unroll
    for (int h = 0; h < 2; ++h) {
        int4 xi = *(const int4*)&x[(t0 + h * 16 + c) * MDIM + g * 4];
        aF[h] = pk4((float)xi.x, (float)xi.y, (float)xi.z, (float)xi.w);
    }
    // lam rows for this lane's m-quad: d3 = c&7 fixed; d1 in {2wv, 2wv+1}
    const float4 l3  = *(const float4*)&lam3[(c & 7) * MDIM + g * 4];
    const float4 l1a = *(const float4*)&lam1[(2 * wv) * MDIM + g * 4];
    const float4 l1b = *(const float4*)&lam1[(2 * wv + 1) * MDIM + g * 4];

    __syncthreads();   // lgtbl + lgred ready
    {
        int xv = x[t0 * MDIM + tid];
        double lg = (double)lgtbl[xv & 31];
        lg = waveSumD(lg);
        if (lane == 0) atomicAdd(&lgred, (float)lg);
    }

    // ---- MFMA phase: em4[h][st] = x-tile(h) @ llc-tile(st)^T - ls ----
    floatx4 em4[2][16];
    #pragma unroll
    for (int st = 0; st < 16; ++st) {
        const int d2 = ((wv << 5) + (st << 1) + (c >> 3)) & 15;
        const float4 l2 = *(const float4*)&lam2[d2 * MDIM + g * 4];
        const float4 l1 = (st < 8) ? l1a : l1b;
        const float la0 = l1.x + l2.x + l3.x;
        const float la1 = l1.y + l2.y + l3.y;
        const float la2 = l1.z + l2.z + l3.z;
        const float la3 = l1.w + l2.w + l3.w;
        float lsp = la0 + la1 + la2 + la3;
        lsp += __shfl_xor(lsp, 16, 64);
        lsp += __shfl_xor(lsp, 32, 64);
        const float ll0 = __logf(la0), ll1 = __logf(la1);
        const float ll2 = __logf(la2), ll3 = __logf(la3);
        short4v bh, bl;
        bh[0] = f2bfs(ll0); bl[0] = f2bfs(ll0 - bfl((uint)(ushort)bh[0]));
        bh[1] = f2bfs(ll1); bl[1] = f2bfs(ll1 - bfl((uint)(ushort)bh[1]));
        bh[2] = f2bfs(ll2); bl[2] = f2bfs(ll2 - bfl((uint)(ushort)bh[2]));
        bh[3] = f2bfs(ll3); bl[3] = f2bfs(ll3 - bfl((uint)(ushort)bh[3]));
        #pragma unroll
        for (int h = 0; h < 2; ++h) {
            floatx4 acc = {-lsp, -lsp, -lsp, -lsp};
            acc = MFMA16(aF[h], bh, acc);
            acc = MFMA16(aF[h], bl, acc);
            em4[h][st] = acc;
        }
    }

    // ---- Dem: per t-row max over all s. lane reg r -> t = h*16 + g*4 + r ----
    #pragma unroll
    for (int h = 0; h < 2; ++h)
        #pragma unroll
        for (int r = 0; r < 4; ++r) {
            float m = em4[h][0][r];
            #pragma unroll
            for (int st = 1; st < 16; ++st) m = fmaxf(m, em4[h][st][r]);
            m = fmaxf(m, __shfl_xor(m, 1, 64));
            m = fmaxf(m, __shfl_xor(m, 2, 64));
            m = fmaxf(m, __shfl_xor(m, 4, 64));
            m = fmaxf(m, __shfl_xor(m, 8, 64));
            if (c == 0) wmx[h * 16 + g * 4 + r][wv] = m;
        }
    __syncthreads();
    if (tid < 32) {
        float m = wmx[tid][0];
        #pragma unroll
        for (int i = 1; i < 8; ++i) m = fmaxf(m, wmx[tid][i]);
        DemS[tid] = m;
    }
    __syncthreads();

    // ---- output: exp, pair-packed b32 slot-permute via Pstg, flush ----
    #pragma unroll
    for (int h = 0; h < 2; ++h) {
        if (h == 1) __syncthreads();      // Pstg reuse: prior flush reads done
        float dd[4];
        #pragma unroll
        for (int r = 0; r < 4; ++r) dd[r] = DemS[h * 16 + g * 4 + r];
        #pragma unroll
        for (int stp = 0; stp < 8; ++stp) {
            const int base = 64 * stp + 16 * (wv >> 1) + c;
            const int uix  = base * 2 + (wv & 1);
            #pragma unroll
            for (int r = 0; r < 4; ++r) {
                float plo = __expf(em4[h][stp][r]     - dd[r]);
                float phi = __expf(em4[h][stp + 8][r] - dd[r]);
                Pstg32[(g * 4 + r) * 1024 + uix] = pkbf(plo, phi);
            }
        }
        __syncthreads();                  // Pstg complete
        #pragma unroll
        for (int it = 0; it < 8; ++it) {
            const int flat = it * 512 + tid;
            uint4 v = ((const uint4*)Pstg)[flat];
            *(uint4*)(P + (size_t)(t0 + h * 16) * SD + flat * 8) = v;
        }
    }

    if (tid == 0) {
        double sumD = 0.0;
        #pragma unroll
        for (int i = 0; i < 32; ++i) sumD += (double)DemS[i];
        SumAuxArr[blockIdx.x] = (float)sumD - lgred;
        if (blockIdx.x == 0) out[0] = 0.f;
    }
}

// ---- K3: TWO-CHUNK interleaved forward recurrence. grid = CHKB(512) x 512.
// [R10/R13/R14-verified structure, absmax 0.0] — only change: WUP 4->2
// (NS 19->17). Parity invariants hold (tA0=32b-2, tB0=32b+14 even; guards
// s>WUP; even-s pair-telescoping tiles exactly, tail covers (16,17)).
__global__ __launch_bounds__(512, 4)
void fhmm_chunk_kernel(const ushort* __restrict__ P,
                       const float* __restrict__ SumAuxArr,
                       const float* __restrict__ logA1,
                       const float* __restrict__ logA2,
                       const float* __restrict__ logA3,
                       const float* __restrict__ logpi1,
                       const float* __restrict__ logpi2,
                       const float* __restrict__ logpi3,
                       float* __restrict__ out)
{
    __shared__ __align__(16) short c1bA[2 * 2048];  // chunk A parity double buffer
    __shared__ __align__(16) short c1bB[2 * 2048];  // chunk B parity double buffer
    __shared__ float wmAA[8], wmAB[8];              // odd steps write, even read
    __shared__ float sred[8];
    __shared__ float saux8[8];

    const int tid  = threadIdx.x;
    const int lane = tid & 63;
    const int wv   = tid >> 6;
    const int q    = lane >> 4;
    const int ml   = lane & 15;

    const int b   = blockIdx.x;
    const int tA0 = (b == 0) ? 0 : 32 * b - WUP;
    const int tB0 = 32 * b + (CLEN - WUP);

    // S1 constants (K=16): B[k=p1=4q+j][n=d1'=ml] = exp(logA1[ml][4q+j])
    short4v bA1k;
    #pragma unroll
    for (int j = 0; j < 4; ++j)
        bA1k[j] = f2bfs(__expf(logA1[ml * 16 + 4 * q + j]));

    // S23 constants, 4 K-chunks: k' = 32jc + 8q + i -> p2 = 4jc+q, p3 = i
    const int d2p = 2 * wv + (ml >> 3);
    const int d3p = ml & 7;
    short8 bK[4];
    #pragma unroll
    for (int jc = 0; jc < 4; ++jc)
        #pragma unroll
        for (int i = 0; i < 8; ++i)
            bK[jc][i] = f2bfs(__expf(logA2[d2p * 16 + 4 * jc + q] + logA3[d3p * 8 + i]));

    // S1 D write offset  [R9/R10-verified]
    const int oS1w = ml * 128 + ((((2 * wv + (q >> 1)) ^ ml) & 15) << 3) + 4 * (q & 1);
    // S23 A-frag offsets [R9/R10-verified]
    int o23[4];
    #pragma unroll
    for (int jc = 0; jc < 4; ++jc)
        o23[jc] = ml * 128 + ((((4 * jc + q) ^ ml) & 15) << 3);

    // block 0: reduce the 512 per-block emission partials (consumed in tail)
    if (b == 0) {
        float sx = waveSumF(SumAuxArr[tid]);
        if (lane == 0) saux8[wv] = sx;
    }

    // ---- init both chunks ----
    double OFF = 0.0;
    float nuA[4], nuB[4];
    {
        uintx2 p0 = *(const uintx2*)(P + (size_t)tA0 * SD + tid * 4);
        if (b == 0) {   // exact: beta_0 = P_0 * pi
            float lp23 = logpi2[d2p] + logpi3[d3p];
            nuA[0] = bfl(p0.x) * __expf(logpi1[4 * q + 0] + lp23);
            nuA[1] = bfh(p0.x) * __expf(logpi1[4 * q + 1] + lp23);
            nuA[2] = bfl(p0.y) * __expf(logpi1[4 * q + 2] + lp23);
            nuA[3] = bfh(p0.y) * __expf(logpi1[4 * q + 3] + lp23);
        } else {
            nuA[0] = bfl(p0.x); nuA[1] = bfh(p0.x);
            nuA[2] = bfl(p0.y); nuA[3] = bfh(p0.y);
        }
    }
    {
        uintx2 p0 = *(const uintx2*)(P + (size_t)tB0 * SD + tid * 4);
        nuB[0] = bfl(p0.x); nuB[1] = bfh(p0.x);
        nuB[2] = bfl(p0.y); nuB[3] = bfh(p0.y);
    }

    // 2-deep P prefetch per chunk
    uintx2 PbA0 = *(const uintx2*)(P + (size_t)(tA0 + 1) * SD + tid * 4);
    uintx2 PbA1 = *(const uintx2*)(P + (size_t)(tA0 + 2) * SD + tid * 4);
    uintx2 PbB0 = *(const uintx2*)(P + (size_t)(tB0 + 1) * SD + tid * 4);
    uintx2 PbB1 = *(const uintx2*)(P + (size_t)(tB0 + 2) * SD + tid * 4);

#define SSTEP(S, RESC, ACCFA, ACCFB)                                            \
{                                                                               \
    const int par = (S) & 1;                                                    \
    short* cAq = c1bA + (par << 11);                                            \
    short* cBq = c1bB + (par << 11);                                            \
    {   /* Stage 1, both chunks, from registers */                              \
        short4v afA = pk4(nuA[0], nuA[1], nuA[2], nuA[3]);                      \
        short4v afB = pk4(nuB[0], nuB[1], nuB[2], nuB[3]);                      \
        floatx4 sA = {0.f, 0.f, 0.f, 0.f};                                      \
        floatx4 sB = {0.f, 0.f, 0.f, 0.f};                                      \
        sA = MFMA16(afA, bA1k, sA);                                             \
        sB = MFMA16(afB, bA1k, sB);                                             \
        ((uintx2*)(cAq + oS1w))[0] = (uintx2){pkbf(sA[0], sA[1]), pkbf(sA[2], sA[3])}; \
        ((uintx2*)(cBq + oS1w))[0] = (uintx2){pkbf(sB[0], sB[1]), pkbf(sB[2], sB[3])}; \
    }                                                                           \
    __syncthreads();                                                            \
    const int tnA = (tA0 + (S) + 2 < TMAX) ? tA0 + (S) + 2 : TMAX - 1;          \
    const int tnB = (tB0 + (S) + 2 < TMAX) ? tB0 + (S) + 2 : TMAX - 1;          \
    uintx2 PbA2 = *(const uintx2*)(P + (size_t)tnA * SD + tid * 4);             \
    uintx2 PbB2 = *(const uintx2*)(P + (size_t)tnB * SD + tid * 4);             \
    float invA = 1.f, invB = 1.f;                                               \
    if (RESC) {                                                                 \
        float mpA = waveMax64(wmAA[lane & 7]);                                  \
        float mpB = waveMax64(wmAB[lane & 7]);                                  \
        float mgA = fmaxf(mpA, 1e-30f);                                         \
        float mgB = fmaxf(mpB, 1e-30f);                                         \
        invA = __builtin_amdgcn_rcpf(mgA);                                      \
        invB = __builtin_amdgcn_rcpf(mgB);                                      \
        if (tid == 0) {                                                         \
            if (ACCFA) OFF += (double)__logf(mgA);                              \
            if (ACCFB) OFF += (double)__logf(mgB);                              \
        }                                                                       \
    }                                                                           \
    {   /* Stage 2+3, both chunks: issue all 8 reads, then 8 MFMAs */           \
        short8 fA0 = *(const short8*)(cAq + o23[0]);                            \
        short8 fA1 = *(const short8*)(cAq + o23[1]);                            \
        short8 fA2 = *(const short8*)(cAq + o23[2]);                            \
        short8 fA3 = *(const short8*)(cAq + o23[3]);                            \
        short8 fB0 = *(const short8*)(cBq + o23[0]);                            \
        short8 fB1 = *(const short8*)(cBq + o23[1]);                            \
        short8 fB2 = *(const short8*)(cBq + o23[2]);                            \
        short8 fB3 = *(const short8*)(cBq + o23[3]);                            \
        floatx4 aA0 = {0.f, 0.f, 0.f, 0.f};                                     \
        floatx4 aA1 = {0.f, 0.f, 0.f, 0.f};                                     \
        floatx4 aB0 = {0.f, 0.f, 0.f, 0.f};                                     \
        floatx4 aB1 = {0.f, 0.f, 0.f, 0.f};                                     \
        aA0 = MFMA32(fA0, bK[0], aA0);  aB0 = MFMA32(fB0, bK[0], aB0);          \
        aA1 = MFMA32(fA1, bK[1], aA1);  aB1 = MFMA32(fB1, bK[1], aB1);          \
        aA0 = MFMA32(fA2, bK[2], aA0);  aB0 = MFMA32(fB2, bK[2], aB0);          \
        aA1 = MFMA32(fA3, bK[3], aA1);  aB1 = MFMA32(fB3, bK[3], aB1);          \
        floatx4 accA = aA0 + aA1;                                               \
        floatx4 accB = aB0 + aB1;                                               \
        if (RESC) {                                                             \
            nuA[0] = bfl(PbA0.x) * accA[0] * invA;                              \
            nuA[1] = bfh(PbA0.x) * accA[1] * invA;                              \
            nuA[2] = bfl(PbA0.y) * accA[2] * invA;                              \
            nuA[3] = bfh(PbA0.y) * accA[3] * invA;                              \
            nuB[0] = bfl(PbB0.x) * accB[0] * invB;                              \
            nuB[1] = bfh(PbB0.x) * accB[1] * invB;                              \
            nuB[2] = bfl(PbB0.y) * accB[2] * invB;                              \
            nuB[3] = bfh(PbB0.y) * accB[3] * invB;                              \
        } else {                                                                \
            nuA[0] = bfl(PbA0.x) * accA[0];                                     \
            nuA[1] = bfh(PbA0.x) * accA[1];                                     \
            nuA[2] = bfl(PbA0.y) * accA[2];                                     \
            nuA[3] = bfh(PbA0.y) * accA[3];                                     \
            nuB[0] = bfl(PbB0.x) * accB[0];                                     \
            nuB[1] = bfh(PbB0.x) * accB[1];                                     \
            nuB[2] = bfl(PbB0.y) * accB[2];                                     \
            nuB[3] = bfh(PbB0.y) * accB[3];                                     \
            float waA = waveMax64(fmaxf(fmaxf(nuA[0], nuA[1]), fmaxf(nuA[2], nuA[3]))); \
            float waB = waveMax64(fmaxf(fmaxf(nuB[0], nuB[1]), fmaxf(nuB[2], nuB[3]))); \
            if (lane == 0) { wmAA[wv] = waA; wmAB[wv] = waB; }                  \
        }                                                                       \
    }                                                                           \
    PbA0 = PbA1; PbA1 = PbA2; PbB0 = PbB1; PbB1 = PbB2;                         \
}

    // s = 1 .. NS(=17); first/last odd (non-RESC), RESC on even s.
    SSTEP(1, false, false, false);
    for (int s = 2; s < NS; s += 2) {
        const bool accfA = (b == 0) || (s > WUP);
        const bool accfB = (s > WUP);
        SSTEP(s, true, accfA, accfB);
        SSTEP(s + 1, false, false, false);
    }
#undef SSTEP

    __syncthreads();

    if (b == CHKB - 1) {     // chunk B here is the LAST chunk: sum path
        float su = waveSumF(nuB[0] + nuB[1] + nuB[2] + nuB[3]);
        if (lane == 0) sred[wv] = su;
        __syncthreads();
        if (tid == 0) {
            float mpA = wmAA[0];
            #pragma unroll
            for (int i = 1; i < 8; ++i) mpA = fmaxf(mpA, wmAA[i]);
            OFF += (double)__logf(fmaxf(mpA, 1e-30f));
            float tot = 0.f;
            #pragma unroll
            for (int i = 0; i < 8; ++i) tot += sred[i];
            OFF += (double)__logf(tot);
            atomicAdd(out, (float)OFF);
        }
    } else {
        if (tid == 0) {
            float mpA = wmAA[0], mpB = wmAB[0];
            #pragma unroll
            for (int i = 1; i < 8; ++i) {
                mpA = fmaxf(mpA, wmAA[i]);
                mpB = fmaxf(mpB, wmAB[i]);
            }
            OFF += (double)__logf(fmaxf(mpA, 1e-30f));
            OFF += (double)__logf(fmaxf(mpB, 1e-30f));
            if (b == 0) {
                float sa = 0.f;
                #pragma unroll
                for (int i = 0; i < 8; ++i) sa += saux8[i];
                OFF += (double)sa;
            }
            atomicAdd(out, (float)OFF);
        }
    }
}

extern "C" void kernel_launch(void* const* d_in, const int* in_sizes, int n_in,
                              void* d_out, int out_size, void* d_ws, size_t ws_size,
                              hipStream_t stream) {
    const int*   x      = (const int*)  d_in[0];
    const float* lam1   = (const float*)d_in[1];
    const float* lam2   = (const float*)d_in[2];
    const float* lam3   = (const float*)d_in[3];
    const float* logA1  = (const float*)d_in[4];
    const float* logA2  = (const float*)d_in[5];
    const float* logA3  = (const float*)d_in[6];
    const float* logpi1 = (const float*)d_in[7];
    const float* logpi2 = (const float*)d_in[8];
    const float* logpi3 = (const float*)d_in[9];
    float* out = (float*)d_out;

    // ws: [SumAuxArr: 512 floats (2KB), pad to 4KB] [P_perm: TMAX*2048*2B = 64MB]
    float*  SumAuxArr = (float*)d_ws;
    ushort* P         = (ushort*)((char*)d_ws + 4096);

    // no memsets: out zeroed by emP block 0; SumAuxArr fully overwritten.
    emP_kernel <<<dim3(TMAX / 32), dim3(512), 0, stream>>>(
        x, lam1, lam2, lam3, P, SumAuxArr, out);
    fhmm_chunk_kernel<<<dim3(CHKB), dim3(512), 0, stream>>>(
        P, SumAuxArr, logA1, logA2, logA3, logpi1, logpi2, logpi3, out);
}